// Round 11
// baseline (283.436 us; speedup 1.0000x reference)
//
#include <hip/hip_runtime.h>
#include <hip/hip_bf16.h>
#include <math.h>

#define B 4
#define T 1024
#define KDIM 64
#define R 32
#define NH 8
#define NEGBIG (-1e30f)

typedef __hip_bfloat16 bf16;
typedef __attribute__((ext_vector_type(8))) short bf16x8s;
typedef __attribute__((ext_vector_type(4))) float f32x4;

static __device__ __forceinline__ float b2f(bf16 x) { return __bfloat162float(x); }
static __device__ __forceinline__ bf16 f2b(float x) { return __float2bfloat16(x); }
static __device__ __forceinline__ float sigmoidf_(float x) { return 1.0f / (1.0f + __expf(-x)); }
static __device__ __forceinline__ float siluf_(float x) { return x * sigmoidf_(x); }

static __device__ __forceinline__ float waveSum64(float v) {
    #pragma unroll
    for (int m = 32; m >= 1; m >>= 1) v += __shfl_xor(v, m);
    return v;
}

// ---------------- Kernel 1a: x3 = bn(squeeze conv)  +  fused weight prep ----------------
__global__ __launch_bounds__(256) void k1a_x3(const float* __restrict__ x, const float* __restrict__ sqw,
                                              const float* __restrict__ bng, const float* __restrict__ bnb,
                                              const float* __restrict__ wq, const float* __restrict__ wk,
                                              const float* __restrict__ wv, const float* __restrict__ wl,
                                              const float* __restrict__ uniw, const float* __restrict__ ffw1,
                                              const float* __restrict__ ffw2,
                                              float* __restrict__ x3,
                                              bf16* __restrict__ BqT, bf16* __restrict__ BkT,
                                              bf16* __restrict__ BvT, bf16* __restrict__ BlT,
                                              bf16* __restrict__ uniwT, bf16* __restrict__ ffw1T,
                                              bf16* __restrict__ ffw2T) {
    int blk = blockIdx.x;               // 512 blocks
    int b = blk >> 7, t0 = (blk & 127) << 3;
    int row = threadIdx.x >> 5, o = threadIdx.x & 31;
    int tt = t0 + row;
    const float* xr = x + (size_t)(b * T + tt) * KDIM;
    const float* wr = sqw + o * KDIM;
    float acc = 0.f;
    #pragma unroll
    for (int i = 0; i < KDIM; ++i) acc += xr[i] * wr[i];
    const float inv = 0.9999950000374997f; // 1/sqrt(1+1e-5)
    x3[(size_t)(b * T + tt) * R + o] = bng[o] * acc * inv + bnb[o];

    // fused conv-weight conversion (s-major K): 131072 threads x 3 = 393216
    int gid = blk * 256 + threadIdx.x;
    #pragma unroll
    for (int rep = 0; rep < 3; ++rep) {
        int e = gid + rep * 131072;
        if (e < 163840) {
            int oo = e / 320, kk = e - oo * 320;
            int s = kk >> 6, i = kk & 63;
            BqT[e] = f2b(wq[oo * 320 + i * 5 + s]);
        } else if (e < 327680) {
            int e2 = e - 163840;
            int oo = e2 / 320, kk = e2 - oo * 320;
            int s = kk >> 6, i = kk & 63;
            BkT[e2] = f2b(wk[oo * 320 + i * 5 + s]);
        } else if (e < 360448) {
            int e3 = e - 327680;
            BvT[e3] = f2b(wv[e3]);
        } else {
            int e4 = e - 360448;
            BlT[e4] = f2b(wl[e4]);
        }
    }
    // fused epilogue-weight transpose (bf16): uniwT[c][d], ffw1T[j][i], ffw2T[c][j]
    {
        int e = gid;
        if (e < 65536) {
            int c = e >> 10, d = e & 1023;
            uniwT[e] = f2b(uniw[d * 64 + c]);
        } else if (e < 81920) {
            int e2 = e - 65536;
            int j = e2 >> 6, i = e2 & 63;
            ffw1T[e2] = f2b(ffw1[i * 256 + j]);
        } else if (e < 98304) {
            int e3 = e - 81920;
            int c = e3 >> 8, j = e3 & 255;
            ffw2T[e3] = f2b(ffw2[j * 64 + c]);
        }
    }
}

// ---------------- Kernel 1b: depthwise diff + excite conv + gate + pos ----------------
__global__ __launch_bounds__(256) void k1b_xin(const float* __restrict__ x3, const float* __restrict__ dww,
                                               const float* __restrict__ exw, const float* __restrict__ x,
                                               const float* __restrict__ pos, float* __restrict__ xin) {
    __shared__ float sx3[10 * R];
    __shared__ float sxp[8 * R];
    int blk = blockIdx.x;               // 512 blocks
    int b = blk >> 7, t0 = (blk & 127) << 3;
    int tid = threadIdx.x;
    for (int e = tid; e < 320; e += 256) {
        int rr = e >> 5, o = e & 31;
        int tt = t0 + rr;
        sx3[e] = (tt < T) ? x3[(size_t)(b * T + tt) * R + o] : 0.f;
    }
    __syncthreads();
    {
        int rr = tid >> 5, o = tid & 31;
        int tt = t0 + rr;
        float v;
        if (tt == T - 1) {
            v = sx3[rr * R + o];
        } else {
            float w0 = dww[o * 3 + 0], w1 = dww[o * 3 + 1], w2 = dww[o * 3 + 2];
            v = sx3[rr * R + o] * (w0 - 1.f) + sx3[(rr + 1) * R + o] * w1 + sx3[(rr + 2) * R + o] * w2;
        }
        sxp[rr * R + o] = v;
    }
    __syncthreads();
    int rr = tid >> 5, c0 = tid & 31;
    int tt = t0 + rr;
    #pragma unroll
    for (int u = 0; u < 2; ++u) {
        int c = c0 + u * 32;
        const float* ew = exw + c * R;
        float g = 0.f;
        #pragma unroll
        for (int o = 0; o < R; ++o) g += ew[o] * sxp[rr * R + o];
        float sg = sigmoidf_(g);
        size_t idx = (size_t)(b * T + tt) * KDIM + c;
        xin[idx] = x[idx] * sg + pos[tt * KDIM + c];
    }
}

// ---------------- Kernel 2 (MFMA): q/k/v/l convs + silu + head-scramble store ----------------
// v is written TRANSPOSED (vt[(n*64+c)*T+p]) for k4's barrier-free PV B-fragments.
__global__ __launch_bounds__(256) void k2_mfma(const float* __restrict__ xin,
        const bf16* __restrict__ BqT, const bf16* __restrict__ BkT,
        const bf16* __restrict__ BvT, const bf16* __restrict__ BlT,
        const float* __restrict__ bq, const float* __restrict__ bk,
        bf16* __restrict__ qo, bf16* __restrict__ ko, bf16* __restrict__ vt, bf16* __restrict__ lo) {
    __shared__ __align__(16) bf16 sX[24][72];
    int blk = blockIdx.x;               // 512 blocks
    int sel = blk >> 8;                 // 0: q+v, 1: k+l
    int b = (blk >> 6) & 3, t0 = (blk & 63) << 4;
    int tid = threadIdx.x, w = tid >> 6, lane = tid & 63;
    int lm = lane & 15, quad = lane >> 4;

    for (int e = tid; e < 1536; e += 256) {
        int rr = e >> 6, ch = e & 63;
        int t = t0 - 8 + rr;
        sX[rr][ch] = f2b((t >= 0) ? xin[((size_t)(b * T) + t) * KDIM + ch] : 0.f);
    }
    __syncthreads();

    bf16x8s aX[10];
    #pragma unroll
    for (int ks = 0; ks < 10; ++ks)
        aX[ks] = *(const bf16x8s*)&sX[lm + 2 * (ks >> 1)][(ks & 1) * 32 + quad * 8];

    const bf16* Bd = sel ? BkT : BqT;
    const float* bias = sel ? bk : bq;
    const bf16* Bp = sel ? BlT : BvT;
    bf16* OutD = sel ? ko : qo;
    const float isg = 0.35355339059327373f; // 1/64^0.25

    for (int nt8 = 0; nt8 < 8; ++nt8) {
        int nt = w * 8 + nt8;
        int o = nt * 16 + lm;
        f32x4 acc = {0.f, 0.f, 0.f, 0.f};
        const bf16* br = Bd + (size_t)o * 320;
        #pragma unroll
        for (int ks = 0; ks < 10; ++ks) {
            bf16x8s bB = *(const bf16x8s*)&br[ks * 32 + quad * 8];
            acc = __builtin_amdgcn_mfma_f32_16x16x32_bf16(aX[ks], bB, acc, 0, 0, 0);
        }
        float bb = bias[o];
        int c = o >> 3, h = o & 7;
        #pragma unroll
        for (int r4 = 0; r4 < 4; ++r4) {
            int tt = t0 + quad * 4 + r4;
            int n = (b << 3) + (tt >> 7);
            int pp = ((tt & 127) << 3) | h;
            OutD[((size_t)n * T + pp) * KDIM + c] = f2b(siluf_(acc[r4] + bb) * isg);
        }
    }
    for (int nt8 = 0; nt8 < 8; ++nt8) {
        int nt = w * 8 + nt8;
        int o = nt * 16 + lm;
        f32x4 acc = {0.f, 0.f, 0.f, 0.f};
        const bf16* br = Bp + (size_t)o * 64;
        #pragma unroll
        for (int ks = 0; ks < 2; ++ks) {
            bf16x8s bB = *(const bf16x8s*)&br[ks * 32 + quad * 8];
            acc = __builtin_amdgcn_mfma_f32_16x16x32_bf16(aX[8 + ks], bB, acc, 0, 0, 0);
        }
        int c = o >> 3, h = o & 7;
        #pragma unroll
        for (int r4 = 0; r4 < 4; ++r4) {
            int tt = t0 + quad * 4 + r4;
            int n = (b << 3) + (tt >> 7);
            int pp = ((tt & 127) << 3) | h;
            float val = siluf_(acc[r4]);
            if (sel == 0)   // v -> transposed layout
                vt[((size_t)n * 64 + c) * T + pp] = f2b(val);
            else            // l -> row-major
                lo[((size_t)n * T + pp) * KDIM + c] = f2b(val);
        }
    }
}

// ---------------- Kernel 3: local windowed causal attention (window 5) ----------------
__global__ __launch_bounds__(256) void k3_local(const bf16* __restrict__ lws, bf16* __restrict__ ol) {
    int wave = threadIdx.x >> 6, lane = threadIdx.x & 63;
    int ridx = blockIdx.x * 4 + wave;   // 8192 blocks -> 32768 rows
    int n = ridx >> 10, p = ridx & 1023;
    const bf16* base = lws + (size_t)n * T * KDIM;
    float lp = b2f(base[(size_t)p * KDIM + lane]);
    float lj[6], s[6];
    #pragma unroll
    for (int u = 0; u < 6; ++u) {
        int j = p - 5 + u;
        bool valid = (j >= 0);
        lj[u] = valid ? b2f(base[(size_t)j * KDIM + lane]) : 0.f;
        float d = lp * lj[u];
        d = waveSum64(d);
        s[u] = valid ? d * 0.125f : NEGBIG;
    }
    float mx = s[5];
    #pragma unroll
    for (int u = 0; u < 5; ++u) mx = fmaxf(mx, s[u]);
    float Z = 0.f, acc = 0.f;
    #pragma unroll
    for (int u = 0; u < 6; ++u) {
        float e = (s[u] <= NEGBIG) ? 0.f : __expf(s[u] - mx);
        Z += e;
        acc += e * lj[u];
    }
    ol[(size_t)(n * T + p) * KDIM + lane] = f2b(acc / Z);
}

// ---------------- Kernel 4 (MFMA, barrier-free): global causal flash attention ----------------
// One wave = one (n, 16-row q-tile). No __syncthreads: Q/K/V fragments loaded directly
// from global (L2-resident); only wave-private LDS sPt for the P C->A layout round-trip.
// og aliases q: safe — wave reads only its own 16 q rows (at start) and writes og to
// those same rows (at end); no other wave touches them.
__global__ __launch_bounds__(256) void k4_nobar(const bf16* __restrict__ qws, const bf16* __restrict__ kws,
                                                const bf16* __restrict__ vt, bf16* __restrict__ og) {
    __shared__ __align__(16) bf16 sPt[4][16][72];   // per-wave P^T scratch [m][j]
    int w = threadIdx.x >> 6, lane = threadIdx.x & 63;
    int wid = blockIdx.x * 4 + w;        // 2048 waves: n = wid>>6, t16 = wid&63
    int n = wid >> 6, t16 = wid & 63;
    int p0 = t16 << 4;
    int lm = lane & 15, quad = lane >> 4;

    const bf16* qrow = qws + ((size_t)n * T + p0 + lm) * KDIM;
    bf16x8s aQ[2];
    aQ[0] = *(const bf16x8s*)&qrow[quad * 8];
    aQ[1] = *(const bf16x8s*)&qrow[32 + quad * 8];

    f32x4 O[4];
    float m_i[4], l_i[4];
    #pragma unroll
    for (int t = 0; t < 4; ++t) { O[t][0] = 0.f; O[t][1] = 0.f; O[t][2] = 0.f; O[t][3] = 0.f; }
    #pragma unroll
    for (int r4 = 0; r4 < 4; ++r4) { m_i[r4] = NEGBIG; l_i[r4] = 0.f; }

    int jtmax = t16 >> 2;
    int prow_base = p0 + quad * 4;
    for (int jt = 0; jt <= jtmax; ++jt) {
        int j0 = jt << 6;
        bool diag = (jt == jtmax);
        int ntmax = diag ? (t16 & 3) : 3;

        // ---- QK^T: B-fragments straight from global K ----
        f32x4 S[4];
        for (int nt = 0; nt <= ntmax; ++nt) {
            const bf16* krow = kws + ((size_t)n * T + j0 + nt * 16 + lm) * KDIM;
            bf16x8s bK0 = *(const bf16x8s*)&krow[quad * 8];
            bf16x8s bK1 = *(const bf16x8s*)&krow[32 + quad * 8];
            f32x4 acc = {0.f, 0.f, 0.f, 0.f};
            acc = __builtin_amdgcn_mfma_f32_16x16x32_bf16(aQ[0], bK0, acc, 0, 0, 0);
            acc = __builtin_amdgcn_mfma_f32_16x16x32_bf16(aQ[1], bK1, acc, 0, 0, 0);
            S[nt] = acc;
        }
        // ---- mask + online softmax (row = quad*4+r4, col j = j0+nt*16+lm) ----
        float mt[4];
        #pragma unroll
        for (int r4 = 0; r4 < 4; ++r4) mt[r4] = NEGBIG;
        for (int nt = 0; nt <= ntmax; ++nt) {
            int jcol = j0 + nt * 16 + lm;
            #pragma unroll
            for (int r4 = 0; r4 < 4; ++r4) {
                float s = (jcol <= prow_base + r4) ? S[nt][r4] : NEGBIG;
                S[nt][r4] = s;
                mt[r4] = fmaxf(mt[r4], s);
            }
        }
        #pragma unroll
        for (int r4 = 0; r4 < 4; ++r4) {
            float v = mt[r4];
            v = fmaxf(v, __shfl_xor(v, 1)); v = fmaxf(v, __shfl_xor(v, 2));
            v = fmaxf(v, __shfl_xor(v, 4)); v = fmaxf(v, __shfl_xor(v, 8));
            mt[r4] = v;
        }
        float alpha[4], ps[4];
        #pragma unroll
        for (int r4 = 0; r4 < 4; ++r4) {
            float mnew = fmaxf(m_i[r4], mt[r4]);
            alpha[r4] = __expf(m_i[r4] - mnew);
            m_i[r4] = mnew; ps[r4] = 0.f;
        }
        for (int nt = 0; nt <= ntmax; ++nt) {
            #pragma unroll
            for (int r4 = 0; r4 < 4; ++r4) {
                float p = (S[nt][r4] <= NEGBIG) ? 0.f : __expf(S[nt][r4] - m_i[r4]);
                ps[r4] += p;
                sPt[w][quad * 4 + r4][nt * 16 + lm] = f2b(p);
            }
        }
        // diagonal tiles with even (t16&3): PV reads one 16-col tile beyond what was
        // written this iteration — zero it so stale data can't leak in.
        if (diag && !((t16 & 3) & 1)) {
            int ntz = (t16 & 3) + 1;
            #pragma unroll
            for (int r4 = 0; r4 < 4; ++r4)
                sPt[w][quad * 4 + r4][ntz * 16 + lm] = f2b(0.f);
        }
        #pragma unroll
        for (int r4 = 0; r4 < 4; ++r4) {
            float v = ps[r4];
            v += __shfl_xor(v, 1); v += __shfl_xor(v, 2);
            v += __shfl_xor(v, 4); v += __shfl_xor(v, 8);
            l_i[r4] = l_i[r4] * alpha[r4] + v;
        }
        #pragma unroll
        for (int t = 0; t < 4; ++t)
            #pragma unroll
            for (int r4 = 0; r4 < 4; ++r4) O[t][r4] *= alpha[r4];

        __builtin_amdgcn_wave_barrier();   // pin LDS write->read ordering (wave-private)

        // ---- PV: A from wave-private sPt, B straight from global vt ----
        int ksmaxP = diag ? ((t16 & 3) >> 1) : 1;
        for (int ks = 0; ks <= ksmaxP; ++ks) {
            bf16x8s aP = *(const bf16x8s*)&sPt[w][lm][ks * 32 + quad * 8];
            #pragma unroll
            for (int ct = 0; ct < 4; ++ct) {
                const bf16* vrow = vt + ((size_t)n * 64 + ct * 16 + lm) * T + j0 + ks * 32 + quad * 8;
                bf16x8s bV = *(const bf16x8s*)vrow;
                O[ct] = __builtin_amdgcn_mfma_f32_16x16x32_bf16(aP, bV, O[ct], 0, 0, 0);
            }
        }
    }
    // ---- epilogue ----
    #pragma unroll
    for (int r4 = 0; r4 < 4; ++r4) {
        int p = p0 + quad * 4 + r4;
        float inv = 1.f / l_i[r4];
        bf16* ob = og + ((size_t)n * T + p) * KDIM;
        #pragma unroll
        for (int t = 0; t < 4; ++t) ob[t * 16 + lm] = f2b(O[t][r4] * inv);
    }
}

// ---------------- Kernel 5 (MFMA): gate/concat + uni GEMM + LN1 + FF + LN2 ----------------
__global__ __launch_bounds__(256) void k5_mfma(const bf16* __restrict__ og, const bf16* __restrict__ olw,
        const bf16* __restrict__ uniwT, const float* __restrict__ unib, const float* __restrict__ xin,
        const float* __restrict__ ln1g, const float* __restrict__ ln1b,
        const bf16* __restrict__ ffw1T, const float* __restrict__ ffb1,
        const bf16* __restrict__ ffw2T, const float* __restrict__ ffb2,
        const float* __restrict__ ln2g, const float* __restrict__ ln2b,
        float* __restrict__ out) {
    __shared__ __align__(16) bf16 sU[16][1032];
    __shared__ float sY[16][68];
    __shared__ __align__(16) bf16 sYb[16][72];
    __shared__ __align__(16) bf16 sH[16][264];
    int blk = blockIdx.x;               // 256 blocks
    int b = blk >> 6, t0 = (blk & 63) << 4;
    int tid = threadIdx.x, w = tid >> 6, lane = tid & 63;
    int lm = lane & 15, quad = lane >> 4;

    for (int e = tid; e < 16384; e += 256) {
        int r = e >> 10, d = e & 1023;
        int hh = d >> 6, c = d & 63, hi = hh & 7;
        size_t idx = ((size_t)((b * NH + hi) * T) + t0 + r) * KDIM + c;
        float gv = b2f(og[idx]);
        float sg = sigmoidf_(gv);
        sU[r][d] = f2b((hh < 8) ? (1.f - sg) * b2f(olw[idx]) : sg * gv);
    }
    __syncthreads();

    int col = w * 16 + lm;
    f32x4 accU = {0.f, 0.f, 0.f, 0.f};
    const bf16* ur = uniwT + (size_t)col * 1024;
    #pragma unroll
    for (int ks = 0; ks < 32; ++ks) {
        bf16x8s aU = *(const bf16x8s*)&sU[lm][ks * 32 + quad * 8];
        bf16x8s bU = *(const bf16x8s*)&ur[ks * 32 + quad * 8];
        accU = __builtin_amdgcn_mfma_f32_16x16x32_bf16(aU, bU, accU, 0, 0, 0);
    }
    float ub = unib[col];
    #pragma unroll
    for (int r4 = 0; r4 < 4; ++r4) {
        int row = quad * 4 + r4;
        float a = siluf_(accU[r4] + ub);
        sY[row][col] = a + xin[((size_t)(b * T) + t0 + row) * KDIM + col];
    }
    __syncthreads();

    #pragma unroll
    for (int i = 0; i < 4; ++i) {
        int row = w + 4 * i;
        float yv = sY[row][lane];
        float mean = waveSum64(yv) * (1.f / 64.f);
        float dv = yv - mean;
        float var = waveSum64(dv * dv) * (1.f / 64.f);
        float y = dv * rsqrtf(var + 1e-5f) * ln1g[lane] + ln1b[lane];
        sY[row][lane] = y;
        sYb[row][lane] = f2b(y);
    }
    __syncthreads();

    bf16x8s aY[2];
    #pragma unroll
    for (int ks = 0; ks < 2; ++ks) aY[ks] = *(const bf16x8s*)&sYb[lm][ks * 32 + quad * 8];
    #pragma unroll
    for (int u = 0; u < 4; ++u) {
        int j = (w * 4 + u) * 16 + lm;
        f32x4 acc = {0.f, 0.f, 0.f, 0.f};
        const bf16* fr = ffw1T + (size_t)j * 64;
        #pragma unroll
        for (int ks = 0; ks < 2; ++ks) {
            bf16x8s bF = *(const bf16x8s*)&fr[ks * 32 + quad * 8];
            acc = __builtin_amdgcn_mfma_f32_16x16x32_bf16(aY[ks], bF, acc, 0, 0, 0);
        }
        float b1 = ffb1[j];
        #pragma unroll
        for (int r4 = 0; r4 < 4; ++r4)
            sH[quad * 4 + r4][j] = f2b(fmaxf(acc[r4] + b1, 0.f));
    }
    __syncthreads();

    f32x4 accF = {0.f, 0.f, 0.f, 0.f};
    const bf16* f2r = ffw2T + (size_t)col * 256;
    #pragma unroll
    for (int ks = 0; ks < 8; ++ks) {
        bf16x8s aH = *(const bf16x8s*)&sH[lm][ks * 32 + quad * 8];
        bf16x8s bF2 = *(const bf16x8s*)&f2r[ks * 32 + quad * 8];
        accF = __builtin_amdgcn_mfma_f32_16x16x32_bf16(aH, bF2, accF, 0, 0, 0);
    }
    float b2 = ffb2[col];
    #pragma unroll
    for (int r4 = 0; r4 < 4; ++r4) {
        int row = quad * 4 + r4;
        sY[row][col] = (accF[r4] + b2) + sY[row][col];
    }
    __syncthreads();

    #pragma unroll
    for (int i = 0; i < 4; ++i) {
        int row = w + 4 * i;
        float z = sY[row][lane];
        float mean = waveSum64(z) * (1.f / 64.f);
        float dv = z - mean;
        float var = waveSum64(dv * dv) * (1.f / 64.f);
        out[((size_t)(b * T) + t0 + row) * KDIM + lane] =
            dv * rsqrtf(var + 1e-5f) * ln2g[lane] + ln2b[lane];
    }
}

extern "C" void kernel_launch(void* const* d_in, const int* in_sizes, int n_in,
                              void* d_out, int out_size, void* d_ws, size_t ws_size,
                              hipStream_t stream) {
    (void)in_sizes; (void)n_in; (void)out_size; (void)ws_size;
    const float* x    = (const float*)d_in[0];
    const float* sqw  = (const float*)d_in[1];
    const float* bng  = (const float*)d_in[2];
    const float* bnb  = (const float*)d_in[3];
    const float* dww  = (const float*)d_in[4];
    const float* exw  = (const float*)d_in[5];
    const float* pos  = (const float*)d_in[6];
    const float* wq   = (const float*)d_in[7];
    const float* bq   = (const float*)d_in[8];
    const float* wk   = (const float*)d_in[9];
    const float* bk   = (const float*)d_in[10];
    const float* wv   = (const float*)d_in[11];
    const float* wl   = (const float*)d_in[12];
    const float* uniw = (const float*)d_in[13];
    const float* unib = (const float*)d_in[14];
    const float* ln1g = (const float*)d_in[15];
    const float* ln1b = (const float*)d_in[16];
    const float* ln2g = (const float*)d_in[17];
    const float* ln2b = (const float*)d_in[18];
    const float* ffw1 = (const float*)d_in[19];
    const float* ffb1 = (const float*)d_in[20];
    const float* ffw2 = (const float*)d_in[21];
    const float* ffb2 = (const float*)d_in[22];

    // ws layout — ~22.5 MiB.
    char* ws = (char*)d_ws;
    float* xin   = (float*)(ws);                  // fp32 1.0 MiB
    bf16*  qog   = (bf16*)(ws + 0x100000);        // 4 MiB  q, then og in-place
    bf16*  kw_   = (bf16*)(ws + 0x500000);        // 4 MiB
    bf16*  vtw   = (bf16*)(ws + 0x900000);        // 4 MiB  (transposed v)
    bf16*  lw_   = (bf16*)(ws + 0xD00000);        // 4 MiB
    bf16*  olw   = (bf16*)(ws + 0x1100000);       // 4 MiB
    float* x3    = (float*)(ws + 0x1500000);      // fp32 0.5 MiB
    bf16*  BqT   = (bf16*)(ws + 0x1580000);       // 320 KiB
    bf16*  BkT   = (bf16*)(ws + 0x15D0000);       // 320 KiB
    bf16*  BvT   = (bf16*)(ws + 0x1620000);       // 64 KiB
    bf16*  BlT   = (bf16*)(ws + 0x1630000);       // 64 KiB
    bf16*  uniwT = (bf16*)(ws + 0x1640000);       // 128 KiB
    bf16*  ffw1T = (bf16*)(ws + 0x1660000);       // 32 KiB
    bf16*  ffw2T = (bf16*)(ws + 0x1668000);       // 32 KiB (end 0x1670000)

    k1a_x3 <<<512, 256, 0, stream>>>(x, sqw, bng, bnb, wq, wk, wv, wl, uniw, ffw1, ffw2,
                                     x3, BqT, BkT, BvT, BlT, uniwT, ffw1T, ffw2T);
    k1b_xin<<<512, 256, 0, stream>>>(x3, dww, exw, x, pos, xin);
    k2_mfma<<<512, 256, 0, stream>>>(xin, BqT, BkT, BvT, BlT, bq, bk, qog, kw_, vtw, lw_);
    k3_local<<<8192, 256, 0, stream>>>(lw_, olw);
    k4_nobar<<<512, 256, 0, stream>>>(qog, kw_, vtw, qog);   // og overwrites q in-place
    k5_mfma<<<256, 256, 0, stream>>>(qog, olw, uniwT, unib, xin,
                                     ln1g, ln1b, ffw1T, ffb1, ffw2T, ffb2, ln2g, ln2b,
                                     (float*)d_out);
}

// Round 12
// 236.869 us; speedup vs baseline: 1.1966x; 1.1966x over previous
//
#include <hip/hip_runtime.h>
#include <hip/hip_bf16.h>
#include <math.h>

#define B 4
#define T 1024
#define KDIM 64
#define R 32
#define NH 8
#define NEGBIG (-1e30f)

typedef __hip_bfloat16 bf16;
typedef __attribute__((ext_vector_type(8))) short bf16x8s;
typedef __attribute__((ext_vector_type(4))) short bf16x4s;
typedef __attribute__((ext_vector_type(4))) float f32x4;

static __device__ __forceinline__ float b2f(bf16 x) { return __bfloat162float(x); }
static __device__ __forceinline__ bf16 f2b(float x) { return __float2bfloat16(x); }
static __device__ __forceinline__ float sigmoidf_(float x) { return 1.0f / (1.0f + __expf(-x)); }
static __device__ __forceinline__ float siluf_(float x) { return x * sigmoidf_(x); }

static __device__ __forceinline__ float waveSum64(float v) {
    #pragma unroll
    for (int m = 32; m >= 1; m >>= 1) v += __shfl_xor(v, m);
    return v;
}

// ---------------- Kernel 1a: x3 = bn(squeeze conv)  +  fused weight prep ----------------
__global__ __launch_bounds__(256) void k1a_x3(const float* __restrict__ x, const float* __restrict__ sqw,
                                              const float* __restrict__ bng, const float* __restrict__ bnb,
                                              const float* __restrict__ wq, const float* __restrict__ wk,
                                              const float* __restrict__ wv, const float* __restrict__ wl,
                                              const float* __restrict__ uniw, const float* __restrict__ ffw1,
                                              const float* __restrict__ ffw2,
                                              float* __restrict__ x3,
                                              bf16* __restrict__ BqT, bf16* __restrict__ BkT,
                                              bf16* __restrict__ BvT, bf16* __restrict__ BlT,
                                              bf16* __restrict__ uniwT, bf16* __restrict__ ffw1T,
                                              bf16* __restrict__ ffw2T) {
    int blk = blockIdx.x;               // 512 blocks
    int b = blk >> 7, t0 = (blk & 127) << 3;
    int row = threadIdx.x >> 5, o = threadIdx.x & 31;
    int tt = t0 + row;
    const float* xr = x + (size_t)(b * T + tt) * KDIM;
    const float* wr = sqw + o * KDIM;
    float acc = 0.f;
    #pragma unroll
    for (int i = 0; i < KDIM; ++i) acc += xr[i] * wr[i];
    const float inv = 0.9999950000374997f; // 1/sqrt(1+1e-5)
    x3[(size_t)(b * T + tt) * R + o] = bng[o] * acc * inv + bnb[o];

    // fused conv-weight conversion (s-major K): 131072 threads x 3 = 393216
    int gid = blk * 256 + threadIdx.x;
    #pragma unroll
    for (int rep = 0; rep < 3; ++rep) {
        int e = gid + rep * 131072;
        if (e < 163840) {
            int oo = e / 320, kk = e - oo * 320;
            int s = kk >> 6, i = kk & 63;
            BqT[e] = f2b(wq[oo * 320 + i * 5 + s]);
        } else if (e < 327680) {
            int e2 = e - 163840;
            int oo = e2 / 320, kk = e2 - oo * 320;
            int s = kk >> 6, i = kk & 63;
            BkT[e2] = f2b(wk[oo * 320 + i * 5 + s]);
        } else if (e < 360448) {
            int e3 = e - 327680;
            BvT[e3] = f2b(wv[e3]);
        } else {
            int e4 = e - 360448;
            BlT[e4] = f2b(wl[e4]);
        }
    }
    // fused epilogue-weight transpose (bf16): uniwT[c][d], ffw1T[j][i], ffw2T[c][j]
    {
        int e = gid;
        if (e < 65536) {
            int c = e >> 10, d = e & 1023;
            uniwT[e] = f2b(uniw[d * 64 + c]);
        } else if (e < 81920) {
            int e2 = e - 65536;
            int j = e2 >> 6, i = e2 & 63;
            ffw1T[e2] = f2b(ffw1[i * 256 + j]);
        } else if (e < 98304) {
            int e3 = e - 81920;
            int c = e3 >> 8, j = e3 & 255;
            ffw2T[e3] = f2b(ffw2[j * 64 + c]);
        }
    }
}

// ---------------- Kernel 1b: depthwise diff + excite conv + gate + pos ----------------
__global__ __launch_bounds__(256) void k1b_xin(const float* __restrict__ x3, const float* __restrict__ dww,
                                               const float* __restrict__ exw, const float* __restrict__ x,
                                               const float* __restrict__ pos, float* __restrict__ xin) {
    __shared__ float sx3[10 * R];
    __shared__ float sxp[8 * R];
    int blk = blockIdx.x;               // 512 blocks
    int b = blk >> 7, t0 = (blk & 127) << 3;
    int tid = threadIdx.x;
    for (int e = tid; e < 320; e += 256) {
        int rr = e >> 5, o = e & 31;
        int tt = t0 + rr;
        sx3[e] = (tt < T) ? x3[(size_t)(b * T + tt) * R + o] : 0.f;
    }
    __syncthreads();
    {
        int rr = tid >> 5, o = tid & 31;
        int tt = t0 + rr;
        float v;
        if (tt == T - 1) {
            v = sx3[rr * R + o];
        } else {
            float w0 = dww[o * 3 + 0], w1 = dww[o * 3 + 1], w2 = dww[o * 3 + 2];
            v = sx3[rr * R + o] * (w0 - 1.f) + sx3[(rr + 1) * R + o] * w1 + sx3[(rr + 2) * R + o] * w2;
        }
        sxp[rr * R + o] = v;
    }
    __syncthreads();
    int rr = tid >> 5, c0 = tid & 31;
    int tt = t0 + rr;
    #pragma unroll
    for (int u = 0; u < 2; ++u) {
        int c = c0 + u * 32;
        const float* ew = exw + c * R;
        float g = 0.f;
        #pragma unroll
        for (int o = 0; o < R; ++o) g += ew[o] * sxp[rr * R + o];
        float sg = sigmoidf_(g);
        size_t idx = (size_t)(b * T + tt) * KDIM + c;
        xin[idx] = x[idx] * sg + pos[tt * KDIM + c];
    }
}

// ---------------- Kernel 2 (MFMA): q/k/v/l convs + silu + head-scramble store ----------------
// v is written TRANSPOSED (vt[(n*64+c)*T+p]) so k4 can stage it with vector copies.
__global__ __launch_bounds__(256) void k2_mfma(const float* __restrict__ xin,
        const bf16* __restrict__ BqT, const bf16* __restrict__ BkT,
        const bf16* __restrict__ BvT, const bf16* __restrict__ BlT,
        const float* __restrict__ bq, const float* __restrict__ bk,
        bf16* __restrict__ qo, bf16* __restrict__ ko, bf16* __restrict__ vt, bf16* __restrict__ lo) {
    __shared__ __align__(16) bf16 sX[24][72];
    int blk = blockIdx.x;               // 512 blocks
    int sel = blk >> 8;                 // 0: q+v, 1: k+l
    int b = (blk >> 6) & 3, t0 = (blk & 63) << 4;
    int tid = threadIdx.x, w = tid >> 6, lane = tid & 63;
    int lm = lane & 15, quad = lane >> 4;

    for (int e = tid; e < 1536; e += 256) {
        int rr = e >> 6, ch = e & 63;
        int t = t0 - 8 + rr;
        sX[rr][ch] = f2b((t >= 0) ? xin[((size_t)(b * T) + t) * KDIM + ch] : 0.f);
    }
    __syncthreads();

    bf16x8s aX[10];
    #pragma unroll
    for (int ks = 0; ks < 10; ++ks)
        aX[ks] = *(const bf16x8s*)&sX[lm + 2 * (ks >> 1)][(ks & 1) * 32 + quad * 8];

    const bf16* Bd = sel ? BkT : BqT;
    const float* bias = sel ? bk : bq;
    const bf16* Bp = sel ? BlT : BvT;
    bf16* OutD = sel ? ko : qo;
    const float isg = 0.35355339059327373f; // 1/64^0.25

    for (int nt8 = 0; nt8 < 8; ++nt8) {
        int nt = w * 8 + nt8;
        int o = nt * 16 + lm;
        f32x4 acc = {0.f, 0.f, 0.f, 0.f};
        const bf16* br = Bd + (size_t)o * 320;
        #pragma unroll
        for (int ks = 0; ks < 10; ++ks) {
            bf16x8s bB = *(const bf16x8s*)&br[ks * 32 + quad * 8];
            acc = __builtin_amdgcn_mfma_f32_16x16x32_bf16(aX[ks], bB, acc, 0, 0, 0);
        }
        float bb = bias[o];
        int c = o >> 3, h = o & 7;
        #pragma unroll
        for (int r4 = 0; r4 < 4; ++r4) {
            int tt = t0 + quad * 4 + r4;
            int n = (b << 3) + (tt >> 7);
            int pp = ((tt & 127) << 3) | h;
            OutD[((size_t)n * T + pp) * KDIM + c] = f2b(siluf_(acc[r4] + bb) * isg);
        }
    }
    for (int nt8 = 0; nt8 < 8; ++nt8) {
        int nt = w * 8 + nt8;
        int o = nt * 16 + lm;
        f32x4 acc = {0.f, 0.f, 0.f, 0.f};
        const bf16* br = Bp + (size_t)o * 64;
        #pragma unroll
        for (int ks = 0; ks < 2; ++ks) {
            bf16x8s bB = *(const bf16x8s*)&br[ks * 32 + quad * 8];
            acc = __builtin_amdgcn_mfma_f32_16x16x32_bf16(aX[8 + ks], bB, acc, 0, 0, 0);
        }
        int c = o >> 3, h = o & 7;
        #pragma unroll
        for (int r4 = 0; r4 < 4; ++r4) {
            int tt = t0 + quad * 4 + r4;
            int n = (b << 3) + (tt >> 7);
            int pp = ((tt & 127) << 3) | h;
            float val = siluf_(acc[r4]);
            if (sel == 0)   // v -> transposed layout
                vt[((size_t)n * 64 + c) * T + pp] = f2b(val);
            else            // l -> row-major
                lo[((size_t)n * T + pp) * KDIM + c] = f2b(val);
        }
    }
}

// ---------------- Kernel 3: local windowed causal attention (window 5) ----------------
__global__ __launch_bounds__(256) void k3_local(const bf16* __restrict__ lws, bf16* __restrict__ ol) {
    int wave = threadIdx.x >> 6, lane = threadIdx.x & 63;
    int ridx = blockIdx.x * 4 + wave;   // 8192 blocks -> 32768 rows
    int n = ridx >> 10, p = ridx & 1023;
    const bf16* base = lws + (size_t)n * T * KDIM;
    float lp = b2f(base[(size_t)p * KDIM + lane]);
    float lj[6], s[6];
    #pragma unroll
    for (int u = 0; u < 6; ++u) {
        int j = p - 5 + u;
        bool valid = (j >= 0);
        lj[u] = valid ? b2f(base[(size_t)j * KDIM + lane]) : 0.f;
        float d = lp * lj[u];
        d = waveSum64(d);
        s[u] = valid ? d * 0.125f : NEGBIG;
    }
    float mx = s[5];
    #pragma unroll
    for (int u = 0; u < 5; ++u) mx = fmaxf(mx, s[u]);
    float Z = 0.f, acc = 0.f;
    #pragma unroll
    for (int u = 0; u < 6; ++u) {
        float e = (s[u] <= NEGBIG) ? 0.f : __expf(s[u] - mx);
        Z += e;
        acc += e * lj[u];
    }
    ol[(size_t)(n * T + p) * KDIM + lane] = f2b(acc / Z);
}

// ---------------- Kernel 4 (MFMA, cooperative — R10 structure): causal flash attention ----------------
// Block = one (n, 64-row q-tile); 4 waves x 16 q-rows. og aliases q (safe: q rows staged
// to LDS before any og store; rows owned exclusively by this block).
// Balance swizzle: block i and i+256 (same CU under round-robin dispatch) get q-tiles
// summing to 17 kv-tile iterations (qt + (15-qt) + 2).
__global__ __launch_bounds__(256) void k4_mfma(const bf16* __restrict__ qws, const bf16* __restrict__ kws,
                                               const bf16* __restrict__ vt, bf16* __restrict__ og) {
    __shared__ __align__(16) bf16 sQ[64][72];
    __shared__ __align__(16) bf16 sK[64][72];
    __shared__ __align__(16) bf16 sVt[64][72];   // sVt[c][j] = V[j0+j][c]
    __shared__ __align__(16) bf16 sPt[4][16][76];

    int i = blockIdx.x;                  // 512 blocks
    int half = i >> 8, rem = i & 255;
    int n = rem >> 3, sub = rem & 7;
    int qt = half ? (15 - sub) : sub;
    int p0 = qt << 6;
    int tid = threadIdx.x, w = tid >> 6, lane = tid & 63;
    int lm = lane & 15, quad = lane >> 4;

    const uint4* qg = (const uint4*)(qws + ((size_t)n * T + p0) * KDIM);
    #pragma unroll
    for (int r = 0; r < 2; ++r) { int e = tid + 256 * r; *(uint4*)&sQ[e >> 3][(e & 7) * 8] = qg[e]; }
    __syncthreads();

    bf16x8s aQ[2];
    #pragma unroll
    for (int ks = 0; ks < 2; ++ks) aQ[ks] = *(const bf16x8s*)&sQ[w * 16 + lm][ks * 32 + quad * 8];

    f32x4 O[4];
    float m_i[4], l_i[4];
    #pragma unroll
    for (int t = 0; t < 4; ++t) { O[t][0] = 0.f; O[t][1] = 0.f; O[t][2] = 0.f; O[t][3] = 0.f; }
    #pragma unroll
    for (int r4 = 0; r4 < 4; ++r4) { m_i[r4] = NEGBIG; l_i[r4] = 0.f; }

    for (int jt = 0; jt <= qt; ++jt) {
        int j0 = jt << 6;
        __syncthreads();   // prev iteration's sK/sVt readers done
        const uint4* kg = (const uint4*)(kws + ((size_t)n * T + j0) * KDIM);
        #pragma unroll
        for (int r = 0; r < 2; ++r) { int e = tid + 256 * r; *(uint4*)&sK[e >> 3][(e & 7) * 8] = kg[e]; }
        {
            // V already transposed in global: two 16B vector copies per thread.
            int c = tid >> 2, j8 = tid & 3;
            const bf16* vrow = vt + ((size_t)n * 64 + c) * T + j0 + j8 * 16;
            *(uint4*)&sVt[c][j8 * 16]     = *(const uint4*)vrow;
            *(uint4*)&sVt[c][j8 * 16 + 8] = *(const uint4*)(vrow + 8);
        }
        __syncthreads();

        f32x4 S[4];
        #pragma unroll
        for (int nt = 0; nt < 4; ++nt) {
            f32x4 acc = {0.f, 0.f, 0.f, 0.f};
            #pragma unroll
            for (int ks = 0; ks < 2; ++ks) {
                bf16x8s bK = *(const bf16x8s*)&sK[nt * 16 + lm][ks * 32 + quad * 8];
                acc = __builtin_amdgcn_mfma_f32_16x16x32_bf16(aQ[ks], bK, acc, 0, 0, 0);
            }
            S[nt] = acc;
        }
        float mt[4];
        #pragma unroll
        for (int r4 = 0; r4 < 4; ++r4) mt[r4] = NEGBIG;
        int prow_base = p0 + w * 16 + quad * 4;
        #pragma unroll
        for (int nt = 0; nt < 4; ++nt) {
            int jcol = j0 + nt * 16 + lm;
            #pragma unroll
            for (int r4 = 0; r4 < 4; ++r4) {
                float s = (jcol <= prow_base + r4) ? S[nt][r4] : NEGBIG;
                S[nt][r4] = s;
                mt[r4] = fmaxf(mt[r4], s);
            }
        }
        #pragma unroll
        for (int r4 = 0; r4 < 4; ++r4) {
            float v = mt[r4];
            v = fmaxf(v, __shfl_xor(v, 1)); v = fmaxf(v, __shfl_xor(v, 2));
            v = fmaxf(v, __shfl_xor(v, 4)); v = fmaxf(v, __shfl_xor(v, 8));
            mt[r4] = v;
        }
        float alpha[4], ps[4];
        #pragma unroll
        for (int r4 = 0; r4 < 4; ++r4) {
            float mnew = fmaxf(m_i[r4], mt[r4]);
            alpha[r4] = __expf(m_i[r4] - mnew);
            m_i[r4] = mnew; ps[r4] = 0.f;
        }
        #pragma unroll
        for (int nt = 0; nt < 4; ++nt) {
            #pragma unroll
            for (int r4 = 0; r4 < 4; ++r4) {
                float p = (S[nt][r4] <= NEGBIG) ? 0.f : __expf(S[nt][r4] - m_i[r4]);
                ps[r4] += p;
                sPt[w][quad * 4 + r4][nt * 16 + lm] = f2b(p);
            }
        }
        #pragma unroll
        for (int r4 = 0; r4 < 4; ++r4) {
            float v = ps[r4];
            v += __shfl_xor(v, 1); v += __shfl_xor(v, 2);
            v += __shfl_xor(v, 4); v += __shfl_xor(v, 8);
            l_i[r4] = l_i[r4] * alpha[r4] + v;
        }
        #pragma unroll
        for (int t = 0; t < 4; ++t)
            #pragma unroll
            for (int r4 = 0; r4 < 4; ++r4) O[t][r4] *= alpha[r4];
        int ksmax = (jt == qt) ? (w >> 1) : 1;
        for (int ks = 0; ks <= ksmax; ++ks) {
            bf16x4s plo = *(const bf16x4s*)&sPt[w][lm][ks * 32 + quad * 8];
            bf16x4s phi = *(const bf16x4s*)&sPt[w][lm][ks * 32 + quad * 8 + 4];
            bf16x8s aP;
            #pragma unroll
            for (int ii = 0; ii < 4; ++ii) { aP[ii] = plo[ii]; aP[ii + 4] = phi[ii]; }
            #pragma unroll
            for (int ct = 0; ct < 4; ++ct) {
                bf16x8s bV = *(const bf16x8s*)&sVt[ct * 16 + lm][ks * 32 + quad * 8];
                O[ct] = __builtin_amdgcn_mfma_f32_16x16x32_bf16(aP, bV, O[ct], 0, 0, 0);
            }
        }
    }
    #pragma unroll
    for (int r4 = 0; r4 < 4; ++r4) {
        int p = p0 + w * 16 + quad * 4 + r4;
        float inv = 1.f / l_i[r4];
        bf16* ob = og + ((size_t)n * T + p) * KDIM;
        #pragma unroll
        for (int t = 0; t < 4; ++t) ob[t * 16 + lm] = f2b(O[t][r4] * inv);
    }
}

// ---------------- Kernel 5 (MFMA): gate/concat + uni GEMM + LN1 + FF + LN2 ----------------
__global__ __launch_bounds__(256) void k5_mfma(const bf16* __restrict__ og, const bf16* __restrict__ olw,
        const bf16* __restrict__ uniwT, const float* __restrict__ unib, const float* __restrict__ xin,
        const float* __restrict__ ln1g, const float* __restrict__ ln1b,
        const bf16* __restrict__ ffw1T, const float* __restrict__ ffb1,
        const bf16* __restrict__ ffw2T, const float* __restrict__ ffb2,
        const float* __restrict__ ln2g, const float* __restrict__ ln2b,
        float* __restrict__ out) {
    __shared__ __align__(16) bf16 sU[16][1032];
    __shared__ float sY[16][68];
    __shared__ __align__(16) bf16 sYb[16][72];
    __shared__ __align__(16) bf16 sH[16][264];
    int blk = blockIdx.x;               // 256 blocks
    int b = blk >> 6, t0 = (blk & 63) << 4;
    int tid = threadIdx.x, w = tid >> 6, lane = tid & 63;
    int lm = lane & 15, quad = lane >> 4;

    for (int e = tid; e < 16384; e += 256) {
        int r = e >> 10, d = e & 1023;
        int hh = d >> 6, c = d & 63, hi = hh & 7;
        size_t idx = ((size_t)((b * NH + hi) * T) + t0 + r) * KDIM + c;
        float gv = b2f(og[idx]);
        float sg = sigmoidf_(gv);
        sU[r][d] = f2b((hh < 8) ? (1.f - sg) * b2f(olw[idx]) : sg * gv);
    }
    __syncthreads();

    int col = w * 16 + lm;
    f32x4 accU = {0.f, 0.f, 0.f, 0.f};
    const bf16* ur = uniwT + (size_t)col * 1024;
    #pragma unroll
    for (int ks = 0; ks < 32; ++ks) {
        bf16x8s aU = *(const bf16x8s*)&sU[lm][ks * 32 + quad * 8];
        bf16x8s bU = *(const bf16x8s*)&ur[ks * 32 + quad * 8];
        accU = __builtin_amdgcn_mfma_f32_16x16x32_bf16(aU, bU, accU, 0, 0, 0);
    }
    float ub = unib[col];
    #pragma unroll
    for (int r4 = 0; r4 < 4; ++r4) {
        int row = quad * 4 + r4;
        float a = siluf_(accU[r4] + ub);
        sY[row][col] = a + xin[((size_t)(b * T) + t0 + row) * KDIM + col];
    }
    __syncthreads();

    #pragma unroll
    for (int i = 0; i < 4; ++i) {
        int row = w + 4 * i;
        float yv = sY[row][lane];
        float mean = waveSum64(yv) * (1.f / 64.f);
        float dv = yv - mean;
        float var = waveSum64(dv * dv) * (1.f / 64.f);
        float y = dv * rsqrtf(var + 1e-5f) * ln1g[lane] + ln1b[lane];
        sY[row][lane] = y;
        sYb[row][lane] = f2b(y);
    }
    __syncthreads();

    bf16x8s aY[2];
    #pragma unroll
    for (int ks = 0; ks < 2; ++ks) aY[ks] = *(const bf16x8s*)&sYb[lm][ks * 32 + quad * 8];
    #pragma unroll
    for (int u = 0; u < 4; ++u) {
        int j = (w * 4 + u) * 16 + lm;
        f32x4 acc = {0.f, 0.f, 0.f, 0.f};
        const bf16* fr = ffw1T + (size_t)j * 64;
        #pragma unroll
        for (int ks = 0; ks < 2; ++ks) {
            bf16x8s bF = *(const bf16x8s*)&fr[ks * 32 + quad * 8];
            acc = __builtin_amdgcn_mfma_f32_16x16x32_bf16(aY[ks], bF, acc, 0, 0, 0);
        }
        float b1 = ffb1[j];
        #pragma unroll
        for (int r4 = 0; r4 < 4; ++r4)
            sH[quad * 4 + r4][j] = f2b(fmaxf(acc[r4] + b1, 0.f));
    }
    __syncthreads();

    f32x4 accF = {0.f, 0.f, 0.f, 0.f};
    const bf16* f2r = ffw2T + (size_t)col * 256;
    #pragma unroll
    for (int ks = 0; ks < 8; ++ks) {
        bf16x8s aH = *(const bf16x8s*)&sH[lm][ks * 32 + quad * 8];
        bf16x8s bF2 = *(const bf16x8s*)&f2r[ks * 32 + quad * 8];
        accF = __builtin_amdgcn_mfma_f32_16x16x32_bf16(aH, bF2, accF, 0, 0, 0);
    }
    float b2 = ffb2[col];
    #pragma unroll
    for (int r4 = 0; r4 < 4; ++r4) {
        int row = quad * 4 + r4;
        sY[row][col] = (accF[r4] + b2) + sY[row][col];
    }
    __syncthreads();

    #pragma unroll
    for (int i = 0; i < 4; ++i) {
        int row = w + 4 * i;
        float z = sY[row][lane];
        float mean = waveSum64(z) * (1.f / 64.f);
        float dv = z - mean;
        float var = waveSum64(dv * dv) * (1.f / 64.f);
        out[((size_t)(b * T) + t0 + row) * KDIM + lane] =
            dv * rsqrtf(var + 1e-5f) * ln2g[lane] + ln2b[lane];
    }
}

extern "C" void kernel_launch(void* const* d_in, const int* in_sizes, int n_in,
                              void* d_out, int out_size, void* d_ws, size_t ws_size,
                              hipStream_t stream) {
    (void)in_sizes; (void)n_in; (void)out_size; (void)ws_size;
    const float* x    = (const float*)d_in[0];
    const float* sqw  = (const float*)d_in[1];
    const float* bng  = (const float*)d_in[2];
    const float* bnb  = (const float*)d_in[3];
    const float* dww  = (const float*)d_in[4];
    const float* exw  = (const float*)d_in[5];
    const float* pos  = (const float*)d_in[6];
    const float* wq   = (const float*)d_in[7];
    const float* bq   = (const float*)d_in[8];
    const float* wk   = (const float*)d_in[9];
    const float* bk   = (const float*)d_in[10];
    const float* wv   = (const float*)d_in[11];
    const float* wl   = (const float*)d_in[12];
    const float* uniw = (const float*)d_in[13];
    const float* unib = (const float*)d_in[14];
    const float* ln1g = (const float*)d_in[15];
    const float* ln1b = (const float*)d_in[16];
    const float* ln2g = (const float*)d_in[17];
    const float* ln2b = (const float*)d_in[18];
    const float* ffw1 = (const float*)d_in[19];
    const float* ffb1 = (const float*)d_in[20];
    const float* ffw2 = (const float*)d_in[21];
    const float* ffb2 = (const float*)d_in[22];

    // ws layout — ~22.5 MiB.
    char* ws = (char*)d_ws;
    float* xin   = (float*)(ws);                  // fp32 1.0 MiB
    bf16*  qog   = (bf16*)(ws + 0x100000);        // 4 MiB  q, then og in-place
    bf16*  kw_   = (bf16*)(ws + 0x500000);        // 4 MiB
    bf16*  vtw   = (bf16*)(ws + 0x900000);        // 4 MiB  (transposed v)
    bf16*  lw_   = (bf16*)(ws + 0xD00000);        // 4 MiB
    bf16*  olw   = (bf16*)(ws + 0x1100000);       // 4 MiB
    float* x3    = (float*)(ws + 0x1500000);      // fp32 0.5 MiB
    bf16*  BqT   = (bf16*)(ws + 0x1580000);       // 320 KiB
    bf16*  BkT   = (bf16*)(ws + 0x15D0000);       // 320 KiB
    bf16*  BvT   = (bf16*)(ws + 0x1620000);       // 64 KiB
    bf16*  BlT   = (bf16*)(ws + 0x1630000);       // 64 KiB
    bf16*  uniwT = (bf16*)(ws + 0x1640000);       // 128 KiB
    bf16*  ffw1T = (bf16*)(ws + 0x1660000);       // 32 KiB
    bf16*  ffw2T = (bf16*)(ws + 0x1668000);       // 32 KiB (end 0x1670000)

    k1a_x3 <<<512, 256, 0, stream>>>(x, sqw, bng, bnb, wq, wk, wv, wl, uniw, ffw1, ffw2,
                                     x3, BqT, BkT, BvT, BlT, uniwT, ffw1T, ffw2T);
    k1b_xin<<<512, 256, 0, stream>>>(x3, dww, exw, x, pos, xin);
    k2_mfma<<<512, 256, 0, stream>>>(xin, BqT, BkT, BvT, BlT, bq, bk, qog, kw_, vtw, lw_);
    k3_local<<<8192, 256, 0, stream>>>(lw_, olw);
    k4_mfma<<<512, 256, 0, stream>>>(qog, kw_, vtw, qog);   // og overwrites q in-place
    k5_mfma<<<256, 256, 0, stream>>>(qog, olw, uniwT, unib, xin,
                                     ln1g, ln1b, ffw1T, ffb1, ffw2T, ffb2, ln2g, ln2b,
                                     (float*)d_out);
}